// Round 12
// baseline (151.605 us; speedup 1.0000x reference)
//
#include <hip/hip_runtime.h>
#include <math.h>

#define B_ 2
#define T_ 2048
#define D_ 1024
#define H_ 16
#define DK 64
#define BH_ (B_*H_)

typedef __attribute__((ext_vector_type(8))) short short8;   // 8 bf16 = 4 VGPRs
typedef __attribute__((ext_vector_type(4))) short bf16x4;   // 4 bf16 (NOT short4: HIP class)
typedef __attribute__((ext_vector_type(4))) float fragC;    // MFMA C/D

// 16x16x16 bf16 MFMA (A/B = 4 bf16/lane, k = quad*4+j).
// _1k builtin exists on the device pass only; host pass needs a stub.
#if defined(__HIP_DEVICE_COMPILE__)
#define MFMA16(A,B,C) __builtin_amdgcn_mfma_f32_16x16x16bf16_1k((A),(B),(C),0,0,0)
#else
#define MFMA16(A,B,C) (C)
#endif
#define MFMA32(A,B,C) __builtin_amdgcn_mfma_f32_16x16x32_bf16((A),(B),(C),0,0,0)

__device__ __forceinline__ unsigned short f2bf(float x) {
    union { float f; unsigned u; } c; c.f = x;
    unsigned r = c.u + 0x7fff + ((c.u >> 16) & 1);   // RNE
    return (unsigned short)(r >> 16);
}

__device__ __forceinline__ unsigned pack2bf(float a, float b) {
    return (unsigned)f2bf(a) | ((unsigned)f2bf(b) << 16);
}

// truncating bf16 pair-pack in ONE op: bytes [a.2,a.3,b.2,b.3]
__device__ __forceinline__ unsigned permpack(float a, float b) {
    union { float f; unsigned u; } ca, cb; ca.f = a; cb.f = b;
    return __builtin_amdgcn_perm(cb.u, ca.u, 0x07060302);
}

__device__ __forceinline__ short8 packbf8(float4 a, float4 b) {
    union { short8 v; unsigned u[4]; } r;
    r.u[0] = pack2bf(a.x, a.y); r.u[1] = pack2bf(a.z, a.w);
    r.u[2] = pack2bf(b.x, b.y); r.u[3] = pack2bf(b.z, b.w);
    return r.v;
}

// async global->LDS, 16B per lane
__device__ __forceinline__ void gload_lds16(const void* g, void* l) {
    __builtin_amdgcn_global_load_lds(
        (const __attribute__((address_space(1))) unsigned int*)g,
        (__attribute__((address_space(3))) unsigned int*)l, 16, 0, 0);
}

// ---------------------------------------------------------------------------
// Kernel 0: fp32 -> bf16 for Wp (1M) and Wq/Wk/Wv (196K, repacked
// [h][mat][64][64]).  8 elems/thread, grid 608x256 exact.
// ---------------------------------------------------------------------------
__global__ __launch_bounds__(256) void cvt_kernel(
    const float* __restrict__ Wp,
    const float* __restrict__ Wq, const float* __restrict__ Wk,
    const float* __restrict__ Wv,
    unsigned short* __restrict__ Wb, unsigned short* __restrict__ wqkvb)
{
    const int gid = blockIdx.x * 256 + threadIdx.x;
    const float* src; unsigned short* dst;
    if (gid < 131072) { src = Wp + (size_t)gid * 8; dst = Wb + (size_t)gid * 8; }
    else              { int e = gid - 131072;               // 0..24575
                        int mat = e >> 13, rem = e & 8191;
                        int h = rem >> 9, od = rem & 511;
                        const float* ws = (mat == 0) ? Wq : (mat == 1) ? Wk : Wv;
                        src = ws + ((size_t)(h << 9) + od) * 8;
                        dst = wqkvb + ((size_t)h*1536 + mat*512 + od) * 8; }
    float4 a = *(const float4*)src;
    float4 b = *(const float4*)(src + 4);
    *(uint4*)dst = make_uint4(pack2bf(a.x, a.y), pack2bf(a.z, a.w),
                              pack2bf(b.x, b.y), pack2bf(b.z, b.w));
}

// ---------------------------------------------------------------------------
// Kernel 1: MFMA QKV projection, fp32 x converted in-register.
// R12: grid (32,32) = 1024 blocks (4/CU), wave owns 16 t-rows.
// q (pre-scaled by 0.125*log2e), k: tiled [bh][t/16][dblk(8)][t%16][8].
// v: vt2 layout [bh][kt(32)][dt(4)][ct(4)][quad(4)][n(16)][j(4)].
// ---------------------------------------------------------------------------
__global__ __launch_bounds__(256) void qkv_kernel(
    const float* __restrict__ x,
    const unsigned short* __restrict__ wqkvb,
    unsigned short* __restrict__ q, unsigned short* __restrict__ k,
    unsigned short* __restrict__ vt)
{
    __shared__ unsigned short Wl[3*64*64];       // [mat][out][d], gload layout

    const int bh = blockIdx.x;
    const int b  = bh >> 4, h = bh & 15;
    const int t0 = blockIdx.y * 64;
    const int tid = threadIdx.x;
    const int wave = tid >> 6, lane = tid & 63;
    const int n = lane & 15, quad = lane >> 4;

    // stage this head's 3x64x64 bf16 weights (L2-resident, 24 KB)
    {
        const unsigned short* wsrc = wqkvb + (size_t)h * 12288;
        #pragma unroll
        for (int j = 0; j < 6; ++j) {
            const int off = (wave*6 + j) * 512 + lane*8;
            gload_lds16(wsrc + off, &Wl[off]);
        }
    }

    // x fragments: fp32 loads + RNE pack (lane n <-> t = tw + n)
    const int tw = t0 + wave*16;
    short8 xf[2];
    {
        const float* xr = &x[((size_t)b*T_ + tw + n)*D_ + h*DK];
        float4 a0 = *(const float4*)&xr[quad*8];
        float4 a1 = *(const float4*)&xr[quad*8 + 4];
        xf[0] = packbf8(a0, a1);
        float4 b0 = *(const float4*)&xr[32 + quad*8];
        float4 b1 = *(const float4*)&xr[32 + quad*8 + 4];
        xf[1] = packbf8(b0, b1);
    }
    __syncthreads();

    const float qsc = 0.125f * 1.44269504088896340736f;
    const int tb0 = blockIdx.y*4 + wave;         // tiled t16-block index
    const int ktv = tw >> 6, ctv = (tw >> 4) & 3;
    #pragma unroll
    for (int mat = 0; mat < 3; ++mat) {
        const int wbase = mat * 4096;
        #pragma unroll
        for (int ct = 0; ct < 4; ++ct) {
            short8 wf0 = *(const short8*)&Wl[wbase + (ct*16 + n)*64 + quad*8];
            short8 wf1 = *(const short8*)&Wl[wbase + (ct*16 + n)*64 + 32 + quad*8];
            fragC z = {0.f,0.f,0.f,0.f};
            if (mat < 2) {
                // q^T/k^T: C col = t = n, row = out = ct*16+quad*4+r
                z = MFMA32(wf0, xf[0], z);
                z = MFMA32(wf1, xf[1], z);
                if (mat == 0) {
                    z[0] *= qsc; z[1] *= qsc; z[2] *= qsc; z[3] *= qsc;
                }
                unsigned short* dstg = (mat == 0) ? q : k;
                unsigned short* dp = &dstg[((size_t)bh*128 + tb0)*1024
                                           + (ct*2 + (quad>>1))*128 + n*8 + (quad&1)*4];
                *(uint2*)dp = make_uint2(pack2bf(z[0], z[1]), pack2bf(z[2], z[3]));
            } else {
                // v: C col = d = ct*16+n, row = t = quad*4+r
                z = MFMA32(xf[0], wf0, z);
                z = MFMA32(xf[1], wf1, z);
                unsigned short* dp = &vt[(size_t)bh*131072 + ktv*4096
                                         + ct*1024 + ctv*256 + quad*64 + n*4];
                *(uint2*)dp = make_uint2(pack2bf(z[0], z[1]), pack2bf(z[2], z[3]));
            }
        }
    }
}

// ---------------------------------------------------------------------------
// Kernel 2: causal flash attention, bf16 MFMA, transposed-S + static-max,
// register-resident P.  R12: UNIFORM PAIR decomposition — each block owns
// query-tiles (e, 31-e) sequentially = exactly 33 K-tiles per block (static-
// max softmax makes tiles order/partition free). Grid 512, 2 blocks/CU,
// zero tail (R11: light blocks drained early -> avg occupancy 23.5%).
// ---------------------------------------------------------------------------
__global__ __launch_bounds__(256, 4) void attn_kernel(
    const unsigned short* __restrict__ q, const unsigned short* __restrict__ k,
    const unsigned short* __restrict__ vt, unsigned short* __restrict__ aout)
{
    __shared__ unsigned short Ks[2][4096];      // tiled: [ct][dblk][n][8]
    __shared__ unsigned short Vs[2][4096];      // vt2:   [dt][ct][quad][n][4]

    const int id = blockIdx.x;                  // 0..511
    const int bh = id >> 4;
    const int e  = id & 15;

    const int b   = bh >> 4, h = bh & 15;
    const int tid = threadIdx.x;
    const int wave = tid >> 6, lane = tid & 63;
    const int n = lane & 15, quad = lane >> 4;

    bf16x4 ones4;
    #pragma unroll
    for (int j = 0; j < 4; ++j) ones4[j] = (short)0x3F80;

    const unsigned short* kg = &k[(size_t)bh*131072];
    const unsigned short* vg = &vt[(size_t)bh*131072];

    #pragma unroll
    for (int pass = 0; pass < 2; ++pass) {
        const int qt = pass ? (31 - e) : e;
        const int q0 = qt*64 + wave*16;
        const int nt = qt + 1;

        // Q fragments (tiled layout, pre-scaled)
        const unsigned short* qb = &q[((size_t)bh*128 + qt*4 + wave)*1024 + n*8];
        short8 qf0 = *(const short8*)&qb[quad*128];
        short8 qf1 = *(const short8*)&qb[(4 + quad)*128];

        fragC o[4];                              // O^T: col = query, rows = d
        #pragma unroll
        for (int dt = 0; dt < 4; ++dt) o[dt] = (fragC){0.f,0.f,0.f,0.f};
        fragC l4 = {0.f,0.f,0.f,0.f};

        if (pass) __syncthreads();   // prior pass done reading buf0 before restage
        gload_lds16(kg + tid*8,        &Ks[0][tid*8]);
        gload_lds16(kg + 2048 + tid*8, &Ks[0][2048 + tid*8]);
        gload_lds16(vg + tid*8,        &Vs[0][tid*8]);
        gload_lds16(vg + 2048 + tid*8, &Vs[0][2048 + tid*8]);

        for (int kt = 0; kt < nt; ++kt) {
            __syncthreads();        // drains gloads for buf[kt&1]; syncs readers
            if (kt + 1 < nt) {      // prefetch next tile into other buffer
                const int nb = (kt + 1) & 1;
                const unsigned short* kgn = kg + (size_t)(kt+1)*4096;
                const unsigned short* vgn = vg + (size_t)(kt+1)*4096;
                gload_lds16(kgn + tid*8,        &Ks[nb][tid*8]);
                gload_lds16(kgn + 2048 + tid*8, &Ks[nb][2048 + tid*8]);
                gload_lds16(vgn + tid*8,        &Vs[nb][tid*8]);
                gload_lds16(vgn + 2048 + tid*8, &Vs[nb][2048 + tid*8]);
            }
            const unsigned short* Kb = Ks[kt & 1];
            const unsigned short* Vb = Vs[kt & 1];
            const bool diag = (kt == qt);

            // ---- S^T + softmax -> packed P in registers ----
            bf16x4 pp[4];
            #pragma unroll
            for (int ct = 0; ct < 4; ++ct) {
                short8 kf0 = *(const short8*)&Kb[ct*1024 + quad*128 + n*8];
                short8 kf1 = *(const short8*)&Kb[ct*1024 + 512 + quad*128 + n*8];
                fragC c = {0.f,0.f,0.f,0.f};
                c = MFMA32(kf0, qf0, c);
                c = MFMA32(kf1, qf1, c);
                float p0 = exp2f(c[0]), p1 = exp2f(c[1]);
                float p2 = exp2f(c[2]), p3 = exp2f(c[3]);
                if (diag) {
                    const int lim = (wave*16 + n) - (ct*16 + quad*4);
                    if (0 > lim) p0 = 0.f;
                    if (1 > lim) p1 = 0.f;
                    if (2 > lim) p2 = 0.f;
                    if (3 > lim) p3 = 0.f;
                }
                union { bf16x4 v; unsigned u[2]; } pk;
                pk.u[0] = permpack(p0, p1);
                pk.u[1] = permpack(p2, p3);
                pp[ct] = pk.v;
            }
            // ---- l += sum_key P (ones as A) ----
            #pragma unroll
            for (int ct = 0; ct < 4; ++ct)
                l4 = MFMA16(ones4, pp[ct], l4);
            // ---- O^T += V^T P^T (vf lane-linear b64 from Vs) ----
            #pragma unroll
            for (int dt = 0; dt < 4; ++dt) {
                #pragma unroll
                for (int ct = 0; ct < 4; ++ct) {
                    bf16x4 vf = *(const bf16x4*)&Vb[dt*1024 + ct*256 + quad*64 + n*4];
                    o[dt] = MFMA16(vf, pp[ct], o[dt]);
                }
            }
        }

        // epilogue: col = query = n, rows = d = dt*16+quad*4+r; 8B stores
        const float inv = 1.0f / l4[0];
        unsigned short* dp = &aout[((size_t)b*T_ + q0 + n)*D_ + h*DK + quad*4];
        #pragma unroll
        for (int dt = 0; dt < 4; ++dt) {
            *(uint2*)(dp + dt*16) =
                make_uint2(pack2bf(o[dt][0]*inv, o[dt][1]*inv),
                           pack2bf(o[dt][2]*inv, o[dt][3]*inv));
        }
    }
}

// ---------------------------------------------------------------------------
// Kernel 3: out = A @ Wb^T + bp.   A:[4096,1024] bf16, Wb:[1024,1024] bf16 (B^T)
// R12: 64x128 tiles, grid (64,8) = 512 blocks -> 2 blocks/CU (was 1).
// m97 pattern: global_load_lds width-16 staging + 16x16x32 bf16 MFMA.
// ---------------------------------------------------------------------------
__global__ __launch_bounds__(256) void proj_kernel(
    const unsigned short* __restrict__ A, const unsigned short* __restrict__ Wb,
    const float* __restrict__ bp, float* __restrict__ out)
{
    __shared__ unsigned short As[64*64];        // [row][k]
    __shared__ unsigned short Bs[128*64];       // [col][k]

    const int m0 = blockIdx.x * 64, n0 = blockIdx.y * 128;
    const int tid = threadIdx.x;
    const int wave = tid >> 6, lane = tid & 63;
    const int n = lane & 15, quad = lane >> 4;

    const int srowB = wave*32 + (lane >> 3);    // +i*8, i=0..3  (128 rows)
    const int srowA = wave*16 + (lane >> 3);    // +i*8, i=0..1  (64 rows)
    const int scol  = (lane & 7) * 8;
    const unsigned short* ag = &A [(size_t)(m0 + srowA)*1024 + scol];
    const unsigned short* bg = &Wb[(size_t)(n0 + srowB)*1024 + scol];
    unsigned short* al = &As[(size_t)srowA*64 + scol];
    unsigned short* bl = &Bs[(size_t)srowB*64 + scol];

    fragC acc[4][2];
    #pragma unroll
    for (int i = 0; i < 4; ++i)
        #pragma unroll
        for (int j = 0; j < 2; ++j) acc[i][j] = (fragC){0.f,0.f,0.f,0.f};

    for (int kt = 0; kt < 16; ++kt) {
        __syncthreads();
        #pragma unroll
        for (int i = 0; i < 2; ++i)
            gload_lds16(ag + (size_t)i*8*1024 + kt*64, al + i*8*64);
        #pragma unroll
        for (int i = 0; i < 4; ++i)
            gload_lds16(bg + (size_t)i*8*1024 + kt*64, bl + i*8*64);
        __syncthreads();

        #pragma unroll
        for (int kk = 0; kk < 2; ++kk) {
            short8 af[4], bf[2];
            #pragma unroll
            for (int i = 0; i < 4; ++i)
                af[i] = *(const short8*)&As[(i*16 + n)*64 + kk*32 + quad*8];
            #pragma unroll
            for (int j = 0; j < 2; ++j)
                bf[j] = *(const short8*)&Bs[(wave*32 + j*16 + n)*64 + kk*32 + quad*8];
            #pragma unroll
            for (int i = 0; i < 4; ++i)
                #pragma unroll
                for (int j = 0; j < 2; ++j)
                    acc[i][j] = MFMA32(af[i], bf[j], acc[i][j]);
        }
    }

    #pragma unroll
    for (int i = 0; i < 4; ++i) {
        #pragma unroll
        for (int r = 0; r < 4; ++r) {
            const int m = m0 + i*16 + quad*4 + r;
            #pragma unroll
            for (int j = 0; j < 2; ++j) {
                const int col = n0 + wave*32 + j*16 + n;
                out[(size_t)m*1024 + col] = acc[i][j][r] + bp[col];
            }
        }
    }
}

// ---------------------------------------------------------------------------
extern "C" void kernel_launch(void* const* d_in, const int* in_sizes, int n_in,
                              void* d_out, int out_size, void* d_ws, size_t ws_size,
                              hipStream_t stream)
{
    const float* x  = (const float*)d_in[0];
    const float* Wq = (const float*)d_in[1];
    const float* Wk = (const float*)d_in[2];
    const float* Wv = (const float*)d_in[3];
    const float* Wp = (const float*)d_in[4];
    const float* bp = (const float*)d_in[5];
    float* out = (float*)d_out;

    const size_t per = (size_t)BH_ * T_ * DK;        // 4,194,304 elements
    unsigned short* qws   = (unsigned short*)d_ws;   // bf16, tiled, pre-scaled
    unsigned short* kws   = qws + per;               // bf16, tiled
    unsigned short* vtws  = kws + per;               // bf16, vt2 layout
    unsigned short* aws   = vtws + per;              // [B*T, D] bf16
    unsigned short* wbws  = aws + per;               // Wp bf16 [1024*1024]
    unsigned short* wqkvb = wbws + 1024*1024;        // Wqkv bf16 [16][3][64][64]

    cvt_kernel<<<dim3(608), 256, 0, stream>>>(Wp, Wq, Wk, Wv, wbws, wqkvb);
    qkv_kernel<<<dim3(BH_, T_/64), 256, 0, stream>>>(x, wqkvb, qws, kws, vtws);
    attn_kernel<<<dim3(512), 256, 0, stream>>>(qws, kws, vtws, aws);
    proj_kernel<<<dim3(64, 8), 256, 0, stream>>>(aws, wbws, bp, out);
}

// Round 13
// 150.575 us; speedup vs baseline: 1.0068x; 1.0068x over previous
//
#include <hip/hip_runtime.h>
#include <math.h>

#define B_ 2
#define T_ 2048
#define D_ 1024
#define H_ 16
#define DK 64
#define BH_ (B_*H_)

typedef __attribute__((ext_vector_type(8))) short short8;   // 8 bf16 = 4 VGPRs
typedef __attribute__((ext_vector_type(4))) short bf16x4;   // 4 bf16 (NOT short4: HIP class)
typedef __attribute__((ext_vector_type(4))) float fragC;    // MFMA C/D

// 16x16x16 bf16 MFMA (A/B = 4 bf16/lane, k = quad*4+j).
// _1k builtin exists on the device pass only; host pass needs a stub.
#if defined(__HIP_DEVICE_COMPILE__)
#define MFMA16(A,B,C) __builtin_amdgcn_mfma_f32_16x16x16bf16_1k((A),(B),(C),0,0,0)
#else
#define MFMA16(A,B,C) (C)
#endif
#define MFMA32(A,B,C) __builtin_amdgcn_mfma_f32_16x16x32_bf16((A),(B),(C),0,0,0)

__device__ __forceinline__ unsigned short f2bf(float x) {
    union { float f; unsigned u; } c; c.f = x;
    unsigned r = c.u + 0x7fff + ((c.u >> 16) & 1);   // RNE
    return (unsigned short)(r >> 16);
}

__device__ __forceinline__ unsigned pack2bf(float a, float b) {
    return (unsigned)f2bf(a) | ((unsigned)f2bf(b) << 16);
}

// truncating bf16 pair-pack in ONE op: bytes [a.2,a.3,b.2,b.3]
__device__ __forceinline__ unsigned permpack(float a, float b) {
    union { float f; unsigned u; } ca, cb; ca.f = a; cb.f = b;
    return __builtin_amdgcn_perm(cb.u, ca.u, 0x07060302);
}

__device__ __forceinline__ short8 packbf8(float4 a, float4 b) {
    union { short8 v; unsigned u[4]; } r;
    r.u[0] = pack2bf(a.x, a.y); r.u[1] = pack2bf(a.z, a.w);
    r.u[2] = pack2bf(b.x, b.y); r.u[3] = pack2bf(b.z, b.w);
    return r.v;
}

// async global->LDS, 16B per lane
__device__ __forceinline__ void gload_lds16(const void* g, void* l) {
    __builtin_amdgcn_global_load_lds(
        (const __attribute__((address_space(1))) unsigned int*)g,
        (__attribute__((address_space(3))) unsigned int*)l, 16, 0, 0);
}

// ---------------------------------------------------------------------------
// Kernel 0: fp32 -> bf16 for Wp (1M) and Wq/Wk/Wv (196K, repacked
// [h][mat][64][64]).  8 elems/thread, grid 608x256 exact.
// ---------------------------------------------------------------------------
__global__ __launch_bounds__(256) void cvt_kernel(
    const float* __restrict__ Wp,
    const float* __restrict__ Wq, const float* __restrict__ Wk,
    const float* __restrict__ Wv,
    unsigned short* __restrict__ Wb, unsigned short* __restrict__ wqkvb)
{
    const int gid = blockIdx.x * 256 + threadIdx.x;
    const float* src; unsigned short* dst;
    if (gid < 131072) { src = Wp + (size_t)gid * 8; dst = Wb + (size_t)gid * 8; }
    else              { int e = gid - 131072;               // 0..24575
                        int mat = e >> 13, rem = e & 8191;
                        int h = rem >> 9, od = rem & 511;
                        const float* ws = (mat == 0) ? Wq : (mat == 1) ? Wk : Wv;
                        src = ws + ((size_t)(h << 9) + od) * 8;
                        dst = wqkvb + ((size_t)h*1536 + mat*512 + od) * 8; }
    float4 a = *(const float4*)src;
    float4 b = *(const float4*)(src + 4);
    *(uint4*)dst = make_uint4(pack2bf(a.x, a.y), pack2bf(a.z, a.w),
                              pack2bf(b.x, b.y), pack2bf(b.z, b.w));
}

// ---------------------------------------------------------------------------
// Kernel 1: MFMA QKV projection, fp32 x converted in-register (R11 shape).
// q (pre-scaled by 0.125*log2e), k: tiled [bh][t/16][dblk(8)][t%16][8].
// v: vt2 layout [bh][kt(32)][dt(4)][ct(4)][quad(4)][n(16)][j(4)].
// grid (BH, T/128), block 256 = 4 waves, wave owns 32 t-rows.
// ---------------------------------------------------------------------------
__global__ __launch_bounds__(256) void qkv_kernel(
    const float* __restrict__ x,
    const unsigned short* __restrict__ wqkvb,
    unsigned short* __restrict__ q, unsigned short* __restrict__ k,
    unsigned short* __restrict__ vt)
{
    __shared__ unsigned short Wl[3*64*64];       // [mat][out][d], gload layout

    const int bh = blockIdx.x;
    const int b  = bh >> 4, h = bh & 15;
    const int t0 = blockIdx.y * 128;
    const int tid = threadIdx.x;
    const int wave = tid >> 6, lane = tid & 63;
    const int n = lane & 15, quad = lane >> 4;

    // stage this head's 3x64x64 bf16 weights
    {
        const unsigned short* wsrc = wqkvb + (size_t)h * 12288;
        #pragma unroll
        for (int j = 0; j < 6; ++j) {
            const int off = (wave*6 + j) * 512 + lane*8;
            gload_lds16(wsrc + off, &Wl[off]);
        }
    }

    // x fragments: fp32 loads + RNE pack (lane n <-> t = tw + rt*16 + n)
    const int tw = t0 + wave*32;
    short8 xf[2][2];
    #pragma unroll
    for (int rt = 0; rt < 2; ++rt) {
        const float* xr = &x[((size_t)b*T_ + tw + rt*16 + n)*D_ + h*DK];
        float4 a0 = *(const float4*)&xr[quad*8];
        float4 a1 = *(const float4*)&xr[quad*8 + 4];
        xf[rt][0] = packbf8(a0, a1);
        float4 b0 = *(const float4*)&xr[32 + quad*8];
        float4 b1 = *(const float4*)&xr[32 + quad*8 + 4];
        xf[rt][1] = packbf8(b0, b1);
    }
    __syncthreads();

    const float qsc = 0.125f * 1.44269504088896340736f;
    const int tb0 = blockIdx.y*8 + wave*2;       // tiled t16-block base
    #pragma unroll
    for (int mat = 0; mat < 3; ++mat) {
        const int wbase = mat * 4096;
        #pragma unroll
        for (int ct = 0; ct < 4; ++ct) {
            short8 wf0 = *(const short8*)&Wl[wbase + (ct*16 + n)*64 + quad*8];
            short8 wf1 = *(const short8*)&Wl[wbase + (ct*16 + n)*64 + 32 + quad*8];
            #pragma unroll
            for (int rt = 0; rt < 2; ++rt) {
                fragC z = {0.f,0.f,0.f,0.f};
                if (mat < 2) {
                    // q^T/k^T: C col = t = n, row = out = ct*16+quad*4+r
                    z = MFMA32(wf0, xf[rt][0], z);
                    z = MFMA32(wf1, xf[rt][1], z);
                    if (mat == 0) {
                        z[0] *= qsc; z[1] *= qsc; z[2] *= qsc; z[3] *= qsc;
                    }
                    unsigned short* dstg = (mat == 0) ? q : k;
                    unsigned short* dp = &dstg[((size_t)bh*128 + tb0 + rt)*1024
                                               + (ct*2 + (quad>>1))*128 + n*8 + (quad&1)*4];
                    *(uint2*)dp = make_uint2(pack2bf(z[0], z[1]), pack2bf(z[2], z[3]));
                } else {
                    // v: C col = d = ct*16+n, row = t = quad*4+r
                    z = MFMA32(xf[rt][0], wf0, z);
                    z = MFMA32(xf[rt][1], wf1, z);
                    const int key0 = tw + rt*16;
                    const int ktv = key0 >> 6, ctv = (key0 >> 4) & 3;
                    unsigned short* dp = &vt[(size_t)bh*131072 + ktv*4096
                                             + ct*1024 + ctv*256 + quad*64 + n*4];
                    *(uint2*)dp = make_uint2(pack2bf(z[0], z[1]), pack2bf(z[2], z[3]));
                }
            }
        }
    }
}

// ---------------------------------------------------------------------------
// Kernel 2: causal flash attention, bf16 MFMA, transposed-S + static-max,
// register-resident P.  R13: 128-QUERY BLOCKS — each wave carries two
// 16-query tile sets (rt=0,1) sharing one K/V staging stream of 2qt+2
// tiles.  Halves logical K/V tile-reads (16896 -> 8704) and barrier count
// vs 64q blocks.  Grid 512, heavy/light ordering (same-bh heavy blocks
// adjacent -> L2 K/V sharing, the thing R12's pair scheme broke).
// rt=0 skips the final tile (fully masked); diag = (kt == 2qt+rt) with the
// same local mask formula as R11. (256,2): ~80 VGPR state, no spill risk.
// ---------------------------------------------------------------------------
__global__ __launch_bounds__(256, 2) void attn_kernel(
    const unsigned short* __restrict__ q, const unsigned short* __restrict__ k,
    const unsigned short* __restrict__ vt, unsigned short* __restrict__ aout)
{
    __shared__ unsigned short Ks[2][4096];      // tiled: [ct][dblk][n][8]
    __shared__ unsigned short Vs[2][4096];      // vt2:   [dt][ct][quad][n][4]

    const int id = blockIdx.x;                  // 0..511
    int qt, bh;
    if (id < 256) { bh = id >> 3;         qt = 15 - (id & 7); }
    else          { bh = (id - 256) >> 3; qt = (id - 256) & 7; }

    const int b   = bh >> 4, h = bh & 15;
    const int tid = threadIdx.x;
    const int wave = tid >> 6, lane = tid & 63;
    const int n = lane & 15, quad = lane >> 4;

    // Q fragments for both rt sets (tiled layout, pre-scaled)
    short8 qf[2][2];
    #pragma unroll
    for (int rt = 0; rt < 2; ++rt) {
        const unsigned short* qb =
            &q[((size_t)bh*128 + qt*8 + rt*4 + wave)*1024 + n*8];
        qf[rt][0] = *(const short8*)&qb[quad*128];
        qf[rt][1] = *(const short8*)&qb[(4 + quad)*128];
    }

    fragC o[2][4];                               // O^T: col = query, rows = d
    #pragma unroll
    for (int rt = 0; rt < 2; ++rt)
        #pragma unroll
        for (int dt = 0; dt < 4; ++dt) o[rt][dt] = (fragC){0.f,0.f,0.f,0.f};
    fragC l4[2] = {(fragC){0.f,0.f,0.f,0.f}, (fragC){0.f,0.f,0.f,0.f}};

    bf16x4 ones4;
    #pragma unroll
    for (int j = 0; j < 4; ++j) ones4[j] = (short)0x3F80;

    const unsigned short* kg = &k[(size_t)bh*131072];
    const unsigned short* vg = &vt[(size_t)bh*131072];

    const int nt = 2*qt + 2;
    // stage tile 0 into buffer 0
    gload_lds16(kg + tid*8,        &Ks[0][tid*8]);
    gload_lds16(kg + 2048 + tid*8, &Ks[0][2048 + tid*8]);
    gload_lds16(vg + tid*8,        &Vs[0][tid*8]);
    gload_lds16(vg + 2048 + tid*8, &Vs[0][2048 + tid*8]);

    for (int kt = 0; kt < nt; ++kt) {
        __syncthreads();            // drains gloads for buf[kt&1]; syncs readers
        if (kt + 1 < nt) {          // prefetch next tile into other buffer
            const int nb = (kt + 1) & 1;
            const unsigned short* kgn = kg + (size_t)(kt+1)*4096;
            const unsigned short* vgn = vg + (size_t)(kt+1)*4096;
            gload_lds16(kgn + tid*8,        &Ks[nb][tid*8]);
            gload_lds16(kgn + 2048 + tid*8, &Ks[nb][2048 + tid*8]);
            gload_lds16(vgn + tid*8,        &Vs[nb][tid*8]);
            gload_lds16(vgn + 2048 + tid*8, &Vs[nb][2048 + tid*8]);
        }
        const unsigned short* Kb = Ks[kt & 1];
        const unsigned short* Vb = Vs[kt & 1];

        #pragma unroll
        for (int rt = 0; rt < 2; ++rt) {
            if (rt == 0 && kt == nt - 1) continue;   // fully masked for rt0
            const bool diag = (kt == 2*qt + rt);

            // ---- S^T + softmax -> packed P in registers ----
            bf16x4 pp[4];
            #pragma unroll
            for (int ct = 0; ct < 4; ++ct) {
                short8 kf0 = *(const short8*)&Kb[ct*1024 + quad*128 + n*8];
                short8 kf1 = *(const short8*)&Kb[ct*1024 + 512 + quad*128 + n*8];
                fragC c = {0.f,0.f,0.f,0.f};
                c = MFMA32(kf0, qf[rt][0], c);
                c = MFMA32(kf1, qf[rt][1], c);
                float p0 = exp2f(c[0]), p1 = exp2f(c[1]);
                float p2 = exp2f(c[2]), p3 = exp2f(c[3]);
                if (diag) {
                    const int lim = (wave*16 + n) - (ct*16 + quad*4);
                    if (0 > lim) p0 = 0.f;
                    if (1 > lim) p1 = 0.f;
                    if (2 > lim) p2 = 0.f;
                    if (3 > lim) p3 = 0.f;
                }
                union { bf16x4 v; unsigned u[2]; } pk;
                pk.u[0] = permpack(p0, p1);
                pk.u[1] = permpack(p2, p3);
                pp[ct] = pk.v;
            }
            // ---- l += sum_key P ----
            #pragma unroll
            for (int ct = 0; ct < 4; ++ct)
                l4[rt] = MFMA16(ones4, pp[ct], l4[rt]);
            // ---- O^T += V^T P^T ----
            #pragma unroll
            for (int dt = 0; dt < 4; ++dt) {
                #pragma unroll
                for (int ct = 0; ct < 4; ++ct) {
                    bf16x4 vf = *(const bf16x4*)&Vb[dt*1024 + ct*256 + quad*64 + n*4];
                    o[rt][dt] = MFMA16(vf, pp[ct], o[rt][dt]);
                }
            }
        }
    }

    // epilogue: col = query = n, rows = d = dt*16+quad*4+r; 8B packed stores
    #pragma unroll
    for (int rt = 0; rt < 2; ++rt) {
        const int q0 = qt*128 + rt*64 + wave*16;
        const float inv = 1.0f / l4[rt][0];
        unsigned short* dp = &aout[((size_t)b*T_ + q0 + n)*D_ + h*DK + quad*4];
        #pragma unroll
        for (int dt = 0; dt < 4; ++dt) {
            *(uint2*)(dp + dt*16) =
                make_uint2(pack2bf(o[rt][dt][0]*inv, o[rt][dt][1]*inv),
                           pack2bf(o[rt][dt][2]*inv, o[rt][dt][3]*inv));
        }
    }
}

// ---------------------------------------------------------------------------
// Kernel 3: out = A @ Wb^T + bp.   A:[4096,1024] bf16, Wb:[1024,1024] bf16 (B^T)
// 64x128 tiles, grid (64,8) = 512 blocks -> 2 blocks/CU.
// m97 pattern: global_load_lds width-16 staging + 16x16x32 bf16 MFMA.
// ---------------------------------------------------------------------------
__global__ __launch_bounds__(256) void proj_kernel(
    const unsigned short* __restrict__ A, const unsigned short* __restrict__ Wb,
    const float* __restrict__ bp, float* __restrict__ out)
{
    __shared__ unsigned short As[64*64];        // [row][k]
    __shared__ unsigned short Bs[128*64];       // [col][k]

    const int m0 = blockIdx.x * 64, n0 = blockIdx.y * 128;
    const int tid = threadIdx.x;
    const int wave = tid >> 6, lane = tid & 63;
    const int n = lane & 15, quad = lane >> 4;

    const int srowB = wave*32 + (lane >> 3);    // +i*8, i=0..3  (128 rows)
    const int srowA = wave*16 + (lane >> 3);    // +i*8, i=0..1  (64 rows)
    const int scol  = (lane & 7) * 8;
    const unsigned short* ag = &A [(size_t)(m0 + srowA)*1024 + scol];
    const unsigned short* bg = &Wb[(size_t)(n0 + srowB)*1024 + scol];
    unsigned short* al = &As[(size_t)srowA*64 + scol];
    unsigned short* bl = &Bs[(size_t)srowB*64 + scol];

    fragC acc[4][2];
    #pragma unroll
    for (int i = 0; i < 4; ++i)
        #pragma unroll
        for (int j = 0; j < 2; ++j) acc[i][j] = (fragC){0.f,0.f,0.f,0.f};

    for (int kt = 0; kt < 16; ++kt) {
        __syncthreads();
        #pragma unroll
        for (int i = 0; i < 2; ++i)
            gload_lds16(ag + (size_t)i*8*1024 + kt*64, al + i*8*64);
        #pragma unroll
        for (int i = 0; i < 4; ++i)
            gload_lds16(bg + (size_t)i*8*1024 + kt*64, bl + i*8*64);
        __syncthreads();

        #pragma unroll
        for (int kk = 0; kk < 2; ++kk) {
            short8 af[4], bf[2];
            #pragma unroll
            for (int i = 0; i < 4; ++i)
                af[i] = *(const short8*)&As[(i*16 + n)*64 + kk*32 + quad*8];
            #pragma unroll
            for (int j = 0; j < 2; ++j)
                bf[j] = *(const short8*)&Bs[(wave*32 + j*16 + n)*64 + kk*32 + quad*8];
            #pragma unroll
            for (int i = 0; i < 4; ++i)
                #pragma unroll
                for (int j = 0; j < 2; ++j)
                    acc[i][j] = MFMA32(af[i], bf[j], acc[i][j]);
        }
    }

    #pragma unroll
    for (int i = 0; i < 4; ++i) {
        #pragma unroll
        for (int r = 0; r < 4; ++r) {
            const int m = m0 + i*16 + quad*4 + r;
            #pragma unroll
            for (int j = 0; j < 2; ++j) {
                const int col = n0 + wave*32 + j*16 + n;
                out[(size_t)m*1024 + col] = acc[i][j][r] + bp[col];
            }
        }
    }
}

// ---------------------------------------------------------------------------
extern "C" void kernel_launch(void* const* d_in, const int* in_sizes, int n_in,
                              void* d_out, int out_size, void* d_ws, size_t ws_size,
                              hipStream_t stream)
{
    const float* x  = (const float*)d_in[0];
    const float* Wq = (const float*)d_in[1];
    const float* Wk = (const float*)d_in[2];
    const float* Wv = (const float*)d_in[3];
    const float* Wp = (const float*)d_in[4];
    const float* bp = (const float*)d_in[5];
    float* out = (float*)d_out;

    const size_t per = (size_t)BH_ * T_ * DK;        // 4,194,304 elements
    unsigned short* qws   = (unsigned short*)d_ws;   // bf16, tiled, pre-scaled
    unsigned short* kws   = qws + per;               // bf16, tiled
    unsigned short* vtws  = kws + per;               // bf16, vt2 layout
    unsigned short* aws   = vtws + per;              // [B*T, D] bf16
    unsigned short* wbws  = aws + per;               // Wp bf16 [1024*1024]
    unsigned short* wqkvb = wbws + 1024*1024;        // Wqkv bf16 [16][3][64][64]

    cvt_kernel<<<dim3(608), 256, 0, stream>>>(Wp, Wq, Wk, Wv, wbws, wqkvb);
    qkv_kernel<<<dim3(BH_, T_/128), 256, 0, stream>>>(x, wqkvb, qws, kws, vtws);
    attn_kernel<<<dim3(512), 256, 0, stream>>>(qws, kws, vtws, aws);
    proj_kernel<<<dim3(64, 8), 256, 0, stream>>>(aws, wbws, bp, out);
}